// Round 1
// baseline (748.170 us; speedup 1.0000x reference)
//
#include <hip/hip_runtime.h>
#include <cstdint>

// MultiBoxLoss (SSD) for MI355X.
// Shapes: loc_preds (B,P,4) f32, conf_preds (B,P,C=21) f32, gt_boxes (B,M,4) f32,
//         gt_labels (B,M) i32, default_boxes (P,4) f32. Output: scalar f32.
//
// Pipeline:
//   k_init   : init ws accumulators (ws is re-poisoned 0xAA before every launch)
//   k_match  : per (b,p): IoU vs all M gts -> best_truth (local argmax, first-idx ties);
//              per (b,m): argmax over p via packed u64 atomicMax key (iou_bits<<32 | ~p)
//   k_force  : sequential per-batch forced matches (last-m-wins, matches XLA scatter order)
//   k_loss   : LDS-staged conf chunk -> logsumexp -> ce; pos => smooth-L1(encode) ;
//              writes ce_neg (0 for pos), block-reduced atomics for sums/counts
//   k_select : per-row radix-select k-th largest of ce_neg (k = 3*num_pos_row),
//              sum values >= threshold  (== top-k sum for distinct values)
//   k_final  : (loc + ce_pos + ce_neg_sel) / max(num_pos, 1)

static constexpr int NPB  = 256;  // priors per block
static constexpr int KC   = 21;   // classes (fixed by problem)
static constexpr int MAXM = 64;   // >= M (=50)

__global__ __launch_bounds__(256)
void k_init(unsigned long long* bp_key, int* row_pos, int* pos_total, double* sums,
            int B, int M) {
    int i = blockIdx.x * blockDim.x + threadIdx.x;
    if (i < B * M) bp_key[i] = 0xFFFFFFFFull;  // packed(iou=0, p=0) -> argmax of all-zero col = 0
    if (i < B) row_pos[i] = 0;
    if (i == 0) { *pos_total = 0; sums[0] = 0.0; sums[1] = 0.0; sums[2] = 0.0; }
}

__global__ __launch_bounds__(256)
void k_match(const float4* __restrict__ dbox, const float4* __restrict__ gbox,
             float* __restrict__ bt_iou, int* __restrict__ bt_idx,
             unsigned long long* __restrict__ bp_key, int P, int M) {
    int b = blockIdx.y;
    int t = threadIdx.x;
    int p = blockIdx.x * NPB + t;
    __shared__ float4 sg[MAXM];
    __shared__ float  sga[MAXM];
    __shared__ unsigned long long skey[MAXM];
    if (t < M) {
        float4 g = gbox[b * M + t];
        sg[t]  = g;
        sga[t] = (g.z - g.x) * (g.w - g.y);
        skey[t] = 0ull;
    }
    __syncthreads();
    volatile unsigned* skey_hi = (volatile unsigned*)skey;  // hi dword = iou bits (monotone)
    bool valid = (p < P);
    float4 d = make_float4(0.f, 0.f, 0.f, 0.f);
    float ad = 0.f;
    if (valid) { d = dbox[p]; ad = (d.z - d.x) * (d.w - d.y); }
    float biou = 0.f; int bm = 0;
    if (valid) {
        unsigned invp = 0xFFFFFFFFu - (unsigned)p;  // ties -> smallest p wins (first-occurrence)
        for (int m = 0; m < M; ++m) {
            float4 g = sg[m];
            float lx = fmaxf(d.x, g.x), ly = fmaxf(d.y, g.y);
            float rx = fminf(d.z, g.z), ry = fminf(d.w, g.w);
            float w = fmaxf(rx - lx, 0.f), h = fmaxf(ry - ly, 0.f);
            float inter = w * h;
            float iou = inter / (ad + sga[m] - inter);
            if (iou > biou) { biou = iou; bm = m; }   // strict > : first m wins ties
            if (iou > 0.f) {
                unsigned ib = __float_as_uint(iou);
                // screen on hi word (monotone non-decreasing) before LDS atomic
                if (ib >= skey_hi[2 * m + 1]) {
                    unsigned long long key = ((unsigned long long)ib << 32) | invp;
                    atomicMax(&skey[m], key);
                }
            }
        }
        bt_iou[(size_t)b * P + p] = biou;
        bt_idx[(size_t)b * P + p] = bm;
    }
    __syncthreads();
    if (t < M && skey[t] != 0ull) atomicMax(&bp_key[b * M + t], skey[t]);
}

__global__ __launch_bounds__(64)
void k_force(const unsigned long long* __restrict__ bp_key,
             float* __restrict__ bt_iou, int* __restrict__ bt_idx, int B, int P, int M) {
    int b = blockIdx.x * blockDim.x + threadIdx.x;
    if (b >= B) return;
    for (int m = 0; m < M; ++m) {  // sequential: duplicate p* -> last m wins (scatter order)
        unsigned long long key = bp_key[b * M + m];
        unsigned p = 0xFFFFFFFFu - (unsigned)(key & 0xFFFFFFFFu);
        bt_iou[(size_t)b * P + p] = 1.0f;
        bt_idx[(size_t)b * P + p] = m;
    }
}

__global__ __launch_bounds__(256)
void k_loss(const float* __restrict__ conf, const float4* __restrict__ locp,
            const float4* __restrict__ dbox, const float4* __restrict__ gbox,
            const int* __restrict__ glab,
            const float* __restrict__ bt_iou, const int* __restrict__ bt_idx,
            float* __restrict__ ce_neg, int* __restrict__ row_pos,
            int* __restrict__ pos_total, double* __restrict__ sums,
            int P, int M) {
    int b  = blockIdx.y;
    int t  = threadIdx.x;
    int p0 = blockIdx.x * NPB;
    int npr = min(NPB, P - p0);
    __shared__ float slog[NPB * KC];  // 21.5 KB
    const float* src = conf + ((size_t)b * P + p0) * KC;
    for (int i = t; i < npr * KC; i += NPB) slog[i] = src[i];  // coalesced dword loads
    __syncthreads();
    float sl1 = 0.f, cep = 0.f, posf = 0.f;
    if (t < npr) {
        int p = p0 + t;
        float iou = bt_iou[(size_t)b * P + p];
        int   mi  = bt_idx[(size_t)b * P + p];
        int   lab = (iou < 0.5f) ? 0 : glab[b * M + mi];
        const float* L = slog + t * KC;   // stride 21 (odd) -> 2-way LDS alias, free
        float mx = L[0];
        #pragma unroll
        for (int c = 1; c < KC; ++c) mx = fmaxf(mx, L[c]);
        float s = 0.f;
        #pragma unroll
        for (int c = 0; c < KC; ++c) s += expf(L[c] - mx);
        float lse = mx + logf(s);
        float ce  = lse - L[lab];
        bool pos = lab > 0;
        ce_neg[(size_t)b * P + p] = pos ? 0.f : ce;
        if (pos) {
            posf = 1.f;
            cep  = ce;
            float4 g = gbox[b * M + mi];
            float4 d = dbox[p];
            float gw = g.z - g.x, gh = g.w - g.y;
            float dw = d.z - d.x, dh = d.w - d.y;
            float e0 = (0.5f * (g.x + g.z) - 0.5f * (d.x + d.z)) / (0.1f * dw);
            float e1 = (0.5f * (g.y + g.w) - 0.5f * (d.y + d.w)) / (0.1f * dh);
            float e2 = logf(gw / dw) * 5.0f;  // /0.2
            float e3 = logf(gh / dh) * 5.0f;
            float4 lp = locp[(size_t)b * P + p];
            float d0 = fabsf(lp.x - e0), d1 = fabsf(lp.y - e1);
            float d2 = fabsf(lp.z - e2), d3 = fabsf(lp.w - e3);
            sl1  = (d0 < 1.f ? 0.5f * d0 * d0 : d0 - 0.5f);
            sl1 += (d1 < 1.f ? 0.5f * d1 * d1 : d1 - 0.5f);
            sl1 += (d2 < 1.f ? 0.5f * d2 * d2 : d2 - 0.5f);
            sl1 += (d3 < 1.f ? 0.5f * d3 * d3 : d3 - 0.5f);
        }
    }
    // block reduce (4 waves)
    #pragma unroll
    for (int o = 32; o; o >>= 1) {
        sl1  += __shfl_down(sl1, o);
        cep  += __shfl_down(cep, o);
        posf += __shfl_down(posf, o);
    }
    __shared__ float red[3][4];
    int wid = t >> 6, lane = t & 63;
    if (lane == 0) { red[0][wid] = sl1; red[1][wid] = cep; red[2][wid] = posf; }
    __syncthreads();
    if (t == 0) {
        float A  = red[0][0] + red[0][1] + red[0][2] + red[0][3];
        float Cc = red[1][0] + red[1][1] + red[1][2] + red[1][3];
        float Pp = red[2][0] + red[2][1] + red[2][2] + red[2][3];
        int pc = (int)(Pp + 0.5f);
        if (A  != 0.f) atomicAdd(&sums[0], (double)A);
        if (Cc != 0.f) atomicAdd(&sums[1], (double)Cc);
        if (pc) { atomicAdd(&row_pos[b], pc); atomicAdd(pos_total, pc); }
    }
}

__global__ __launch_bounds__(1024)
void k_select(const float* __restrict__ ce_neg, const int* __restrict__ row_pos,
              double* __restrict__ sums, int P) {
    int b = blockIdx.x;
    int t = threadIdx.x;
    const int NT = 1024;
    __shared__ unsigned hist[256];
    __shared__ unsigned s_prefix;
    __shared__ int s_krem;
    const float* row = ce_neg + (size_t)b * P;
    long long k = 3LL * (long long)row_pos[b];
    unsigned thr;
    if (k <= 0) {
        thr = 0xFFFFFFFFu;          // finite non-neg float bits <= 0x7F800000 -> none selected
    } else if (k >= P) {
        thr = 0u;                   // select all; zeros (positives) add nothing
    } else {
        if (t == 0) { s_prefix = 0u; s_krem = (int)k; }
        __syncthreads();
        for (int d = 3; d >= 0; --d) {   // MSB-first radix select over float bits (all >= 0)
            for (int i = t; i < 256; i += NT) hist[i] = 0u;
            __syncthreads();
            unsigned pre    = s_prefix;
            unsigned maskhi = (d == 3) ? 0u : (0xFFFFFFFFu << ((d + 1) * 8));
            for (int p = t; p < P; p += NT) {
                unsigned bits = __float_as_uint(row[p]);
                if ((bits & maskhi) == pre)
                    atomicAdd(&hist[(bits >> (8 * d)) & 255u], 1u);
            }
            __syncthreads();
            if (t == 0) {
                int krem = s_krem;
                unsigned cum = 0;
                for (int v = 255; v >= 0; --v) {
                    unsigned c = hist[v];
                    if (cum + c >= (unsigned)krem) {
                        s_prefix = pre | ((unsigned)v << (8 * d));
                        s_krem   = krem - (int)cum;
                        break;
                    }
                    cum += c;
                }
            }
            __syncthreads();
        }
        thr = s_prefix;  // exact bits of k-th largest value
    }
    float partial = 0.f;
    for (int p = t; p < P; p += NT) {
        float v = row[p];
        if (__float_as_uint(v) >= thr) partial += v;
    }
    #pragma unroll
    for (int o = 32; o; o >>= 1) partial += __shfl_down(partial, o);
    __shared__ float wsum[16];
    if ((t & 63) == 0) wsum[t >> 6] = partial;
    __syncthreads();
    if (t == 0) {
        float s = 0.f;
        #pragma unroll
        for (int i = 0; i < 16; ++i) s += wsum[i];
        if (s != 0.f) atomicAdd(&sums[2], (double)s);
    }
}

__global__ __launch_bounds__(64)
void k_final(const double* __restrict__ sums, const int* __restrict__ pos_total,
             float* __restrict__ out) {
    if (threadIdx.x == 0 && blockIdx.x == 0) {
        int np = *pos_total;
        if (np < 1) np = 1;
        out[0] = (float)((sums[0] + sums[1] + sums[2]) / (double)np);
    }
}

extern "C" void kernel_launch(void* const* d_in, const int* in_sizes, int n_in,
                              void* d_out, int out_size, void* d_ws, size_t ws_size,
                              hipStream_t stream) {
    const float* loc_preds     = (const float*)d_in[0];
    const float* conf_preds    = (const float*)d_in[1];
    const float* gt_boxes      = (const float*)d_in[2];
    const int*   gt_labels     = (const int*)d_in[3];
    const float* default_boxes = (const float*)d_in[4];

    int P = in_sizes[4] / 4;                // 24564
    int B = in_sizes[0] / (P * 4);          // 64
    int M = in_sizes[3] / B;                // 50

    // workspace carve-out (~19 MB)
    char* w = (char*)d_ws;
    double* sums      = (double*)w;            w += 3 * sizeof(double); // loc, ce_pos, ce_neg
    int*    pos_total = (int*)w;               w += sizeof(int);
    int*    row_pos   = (int*)w;               w += (size_t)B * sizeof(int);
    w = (char*)(((uintptr_t)w + 7) & ~(uintptr_t)7);
    unsigned long long* bp_key = (unsigned long long*)w; w += (size_t)B * M * 8;
    float* bt_iou = (float*)w;                 w += (size_t)B * P * 4;
    int*   bt_idx = (int*)w;                   w += (size_t)B * P * 4;
    float* ce_neg = (float*)w;                 w += (size_t)B * P * 4;

    int nblk = (B * M + 255) / 256;
    k_init<<<nblk, 256, 0, stream>>>(bp_key, row_pos, pos_total, sums, B, M);

    dim3 g1((P + NPB - 1) / NPB, B);
    k_match<<<g1, NPB, 0, stream>>>((const float4*)default_boxes, (const float4*)gt_boxes,
                                    bt_iou, bt_idx, bp_key, P, M);
    k_force<<<1, 64, 0, stream>>>(bp_key, bt_iou, bt_idx, B, P, M);
    k_loss<<<g1, NPB, 0, stream>>>(conf_preds, (const float4*)loc_preds,
                                   (const float4*)default_boxes, (const float4*)gt_boxes,
                                   gt_labels, bt_iou, bt_idx, ce_neg, row_pos, pos_total,
                                   sums, P, M);
    k_select<<<B, 1024, 0, stream>>>(ce_neg, row_pos, sums, P);
    k_final<<<1, 64, 0, stream>>>(sums, pos_total, (float*)d_out);
}

// Round 2
// 685.486 us; speedup vs baseline: 1.0914x; 1.0914x over previous
//
#include <hip/hip_runtime.h>
#include <cstdint>

// MultiBoxLoss (SSD) for MI355X — round 2.
// B=64, P=24564, C=21, M=50. Output: scalar f32.
//
// Pipeline:
//   k_init   : init bp_key / row_pos / pos_total / sums
//   k_match  : per (b,p): IoU vs M gts -> bt_code = (iou>=0.5 ? best_m : -1);
//              per (b,m): argmax over p via packed u64 atomicMax (iou_bits<<32 | ~p)
//   k_force2 : per (b,m): atomicMax(&bt_code[b,p*], FORCED+m)  (max m == last-m-wins)
//   k_loss   : global_load_lds-staged conf chunk -> logsumexp -> ce; pos -> smooth-L1;
//              writes ce_neg (0 for pos); block-reduced atomics for sums/counts
//   k_select : per-row radix-select k-th largest of ce_neg (k=3*row_pos), per-wave
//              histograms + parallel suffix scan; sum values >= threshold
//   k_final  : (loc + ce_pos + ce_neg_sel) / max(num_pos,1)

static constexpr int NPB    = 256;         // priors per block
static constexpr int KC     = 21;          // classes
static constexpr int MAXM   = 64;          // >= M
static constexpr int FORCED = 0x40000000;  // forced-match code offset

typedef unsigned int       u32;
typedef unsigned long long u64;

#define GLOAD_LDS16(gp, lp)                                                        \
  __builtin_amdgcn_global_load_lds((const __attribute__((address_space(1))) u32*)(gp), \
                                   (__attribute__((address_space(3))) u32*)(lp), 16, 0, 0)

__global__ __launch_bounds__(256)
void k_init(u64* bp_key, int* row_pos, int* pos_total, double* sums, int B, int M) {
    int i = blockIdx.x * blockDim.x + threadIdx.x;
    if (i < B * M) bp_key[i] = 0xFFFFFFFFull;  // (iou=0, p=0): argmax of all-zero col = 0
    if (i < B) row_pos[i] = 0;
    if (i == 0) { *pos_total = 0; sums[0] = 0.0; sums[1] = 0.0; sums[2] = 0.0; }
}

__global__ __launch_bounds__(256)
void k_match(const float4* __restrict__ dbox, const float4* __restrict__ gbox,
             int* __restrict__ bt_code, u64* __restrict__ bp_key, int P, int M) {
    int b = blockIdx.y;
    int t = threadIdx.x;
    int p = blockIdx.x * NPB + t;
    __shared__ float4 sg[MAXM];
    __shared__ float  sga[MAXM];
    __shared__ u64    skey[MAXM];
    if (t < M) {
        float4 g = gbox[b * M + t];
        sg[t]  = g;
        sga[t] = (g.z - g.x) * (g.w - g.y);
        skey[t] = 0ull;
    }
    __syncthreads();
    volatile u32* skey_hi = (volatile u32*)skey;  // hi dword = iou bits (monotone)
    if (p < P) {
        float4 d = dbox[p];
        float ad = (d.z - d.x) * (d.w - d.y);
        float biou = 0.f; int bm = 0;
        u32 invp = 0xFFFFFFFFu - (u32)p;  // ties -> smallest p wins
        for (int m = 0; m < M; ++m) {
            float4 g = sg[m];
            float lx = fmaxf(d.x, g.x), ly = fmaxf(d.y, g.y);
            float rx = fminf(d.z, g.z), ry = fminf(d.w, g.w);
            float w = fmaxf(rx - lx, 0.f), h = fmaxf(ry - ly, 0.f);
            float inter = w * h;
            float iou = inter / (ad + sga[m] - inter);
            if (iou > biou) { biou = iou; bm = m; }   // strict > : first m wins ties
            if (iou > 0.f) {
                u32 ib = __float_as_uint(iou);
                if (ib >= skey_hi[2 * m + 1]) {        // screen before LDS atomic
                    u64 key = ((u64)ib << 32) | invp;
                    atomicMax(&skey[m], key);
                }
            }
        }
        bt_code[(size_t)b * P + p] = (biou >= 0.5f) ? bm : -1;
    }
    __syncthreads();
    if (t < M && skey[t] != 0ull) atomicMax(&bp_key[b * M + t], skey[t]);
}

__global__ __launch_bounds__(256)
void k_force2(const u64* __restrict__ bp_key, int* __restrict__ bt_code, int P, int M, int BM) {
    int i = blockIdx.x * blockDim.x + threadIdx.x;
    if (i >= BM) return;
    int b = i / M, m = i - b * M;
    u64 key = bp_key[i];
    u32 p = 0xFFFFFFFFu - (u32)(key & 0xFFFFFFFFu);
    atomicMax(&bt_code[(size_t)b * P + p], FORCED + m);  // max m == sequential last-m-wins
}

__global__ __launch_bounds__(256)
void k_loss(const float* __restrict__ conf, const float4* __restrict__ locp,
            const float4* __restrict__ dbox, const float4* __restrict__ gbox,
            const int* __restrict__ glab, const int* __restrict__ bt_code,
            float* __restrict__ ce_neg, int* __restrict__ row_pos,
            int* __restrict__ pos_total, double* __restrict__ sums, int P, int M) {
    int b  = blockIdx.y;
    int t  = threadIdx.x;
    int p0 = blockIdx.x * NPB;
    int npr = min(NPB, P - p0);
    __shared__ float slog[NPB * KC];  // 21504 B, linear (required by global_load_lds)
    const float* src = conf + ((size_t)b * P + p0) * KC;  // 16B-aligned: p0*84 % 16 == 0
    int nwords = npr * KC;
    int n16 = nwords >> 2;            // 16B chunks (npr % 4 == 0 here -> rem 0)
    for (int i = t; i < n16; i += NPB) GLOAD_LDS16(src + 4 * i, slog + 4 * i);
    int rem = nwords & 3;
    if (t < rem) slog[(n16 << 2) + t] = src[(n16 << 2) + t];
    __syncthreads();  // drains vmcnt(0) -> LDS valid

    float sl1 = 0.f, cep = 0.f, posf = 0.f;
    if (t < npr) {
        int p = p0 + t;
        int code = bt_code[(size_t)b * P + p];
        bool pos = code >= 0;
        int  mi  = (code >= FORCED) ? (code - FORCED) : code;
        const float* L = slog + t * KC;  // stride 21 dwords: odd -> 2-way LDS alias (free)
        float v[KC];
        #pragma unroll
        for (int c = 0; c < KC; ++c) v[c] = L[c];   // static indexing only (no scratch)
        float mx = v[0];
        #pragma unroll
        for (int c = 1; c < KC; ++c) mx = fmaxf(mx, v[c]);
        float s = 0.f;
        #pragma unroll
        for (int c = 0; c < KC; ++c) s += __expf(v[c] - mx);
        int lab = pos ? glab[b * M + mi] : 0;
        float ce = mx + __logf(s) - L[lab];          // runtime index -> one LDS read
        ce_neg[(size_t)b * P + p] = pos ? 0.f : ce;
        if (pos) {
            posf = 1.f;
            cep  = ce;
            float4 g = gbox[b * M + mi];
            float4 d = dbox[p];
            float gw = g.z - g.x, gh = g.w - g.y;
            float dw = d.z - d.x, dh = d.w - d.y;
            float e0 = (0.5f * (g.x + g.z) - 0.5f * (d.x + d.z)) / (0.1f * dw);
            float e1 = (0.5f * (g.y + g.w) - 0.5f * (d.y + d.w)) / (0.1f * dh);
            float e2 = __logf(gw / dw) * 5.0f;  // /VAR1=0.2
            float e3 = __logf(gh / dh) * 5.0f;
            float4 lp = locp[(size_t)b * P + p];
            float d0 = fabsf(lp.x - e0), d1 = fabsf(lp.y - e1);
            float d2 = fabsf(lp.z - e2), d3 = fabsf(lp.w - e3);
            sl1  = (d0 < 1.f ? 0.5f * d0 * d0 : d0 - 0.5f);
            sl1 += (d1 < 1.f ? 0.5f * d1 * d1 : d1 - 0.5f);
            sl1 += (d2 < 1.f ? 0.5f * d2 * d2 : d2 - 0.5f);
            sl1 += (d3 < 1.f ? 0.5f * d3 * d3 : d3 - 0.5f);
        }
    }
    #pragma unroll
    for (int o = 32; o; o >>= 1) {
        sl1  += __shfl_down(sl1, o);
        cep  += __shfl_down(cep, o);
        posf += __shfl_down(posf, o);
    }
    __shared__ float red[3][4];
    int wid = t >> 6, lane = t & 63;
    if (lane == 0) { red[0][wid] = sl1; red[1][wid] = cep; red[2][wid] = posf; }
    __syncthreads();
    if (t == 0) {
        float A  = red[0][0] + red[0][1] + red[0][2] + red[0][3];
        float Cc = red[1][0] + red[1][1] + red[1][2] + red[1][3];
        float Pp = red[2][0] + red[2][1] + red[2][2] + red[2][3];
        int pc = (int)(Pp + 0.5f);
        if (A  != 0.f) atomicAdd(&sums[0], (double)A);
        if (Cc != 0.f) atomicAdd(&sums[1], (double)Cc);
        if (pc) { atomicAdd(&row_pos[b], pc); atomicAdd(pos_total, pc); }
    }
}

__global__ __launch_bounds__(1024)
void k_select(const float* __restrict__ ce_neg, const int* __restrict__ row_pos,
              double* __restrict__ sums, int P) {
    const int NT = 1024, NW = 16;
    int b = blockIdx.x, t = threadIdx.x;
    int wid = t >> 6;
    __shared__ int hist[NW][256];   // per-wave histograms: cuts same-address serialization
    __shared__ int sscan[256];
    __shared__ u32 s_prefix;
    __shared__ int s_krem;
    const float* row = ce_neg + (size_t)b * P;
    int k = 3 * row_pos[b];
    u32 thr;
    if (k <= 0) {
        thr = 0xFFFFFFFFu;   // select none (all finite non-neg bits < 0xFFFFFFFF)
    } else if (k >= P) {
        thr = 0u;            // select all; positives contribute 0
    } else {
        if (t == 0) { s_prefix = 0u; s_krem = k; }
        for (int d = 3; d >= 0; --d) {  // MSB-first radix over float bits (all values >= 0)
            for (int i = t; i < NW * 256; i += NT) ((int*)hist)[i] = 0;
            __syncthreads();
            u32 pre  = s_prefix;
            int krem = s_krem;
            u32 maskhi = (d == 3) ? 0u : (0xFFFFFFFFu << ((d + 1) * 8));
            int sh = 8 * d;
            int* h = hist[wid];
            for (int q = t; q < P; q += 4 * NT) {   // 4-way unrolled: 4 loads in flight
                int q1 = q + NT, q2 = q + 2 * NT, q3 = q + 3 * NT;
                u32 w0 = __float_as_uint(row[q]);
                u32 w1 = (q1 < P) ? __float_as_uint(row[q1]) : 0u;
                u32 w2 = (q2 < P) ? __float_as_uint(row[q2]) : 0u;
                u32 w3 = (q3 < P) ? __float_as_uint(row[q3]) : 0u;
                if ((w0 & maskhi) == pre)            atomicAdd(&h[(w0 >> sh) & 255], 1);
                if (q1 < P && (w1 & maskhi) == pre)  atomicAdd(&h[(w1 >> sh) & 255], 1);
                if (q2 < P && (w2 & maskhi) == pre)  atomicAdd(&h[(w2 >> sh) & 255], 1);
                if (q3 < P && (w3 & maskhi) == pre)  atomicAdd(&h[(w3 >> sh) & 255], 1);
            }
            __syncthreads();
            if (t < 256) {
                int c = 0;
                #pragma unroll
                for (int w = 0; w < NW; ++w) c += hist[w][t];
                sscan[t] = c;
            }
            __syncthreads();
            for (int off = 1; off < 256; off <<= 1) {  // parallel suffix scan (Hillis-Steele)
                int x = 0;
                if (t < 256) { x = sscan[t]; if (t + off < 256) x += sscan[t + off]; }
                __syncthreads();
                if (t < 256) sscan[t] = x;
                __syncthreads();
            }
            if (t < 256) {
                int S  = sscan[t];
                int Sn = (t < 255) ? sscan[t + 1] : 0;
                if (S >= krem && Sn < krem) {   // exactly one bin satisfies
                    s_prefix = pre | ((u32)t << sh);
                    s_krem   = krem - Sn;
                }
            }
            __syncthreads();
        }
        thr = s_prefix;  // bits of k-th largest value
    }
    float partial = 0.f;
    for (int q = t; q < P; q += 4 * NT) {
        int q1 = q + NT, q2 = q + 2 * NT, q3 = q + 3 * NT;
        float v0 = row[q];
        float v1 = (q1 < P) ? row[q1] : 0.f;
        float v2 = (q2 < P) ? row[q2] : 0.f;
        float v3 = (q3 < P) ? row[q3] : 0.f;
        if (__float_as_uint(v0) >= thr)            partial += v0;
        if (q1 < P && __float_as_uint(v1) >= thr)  partial += v1;
        if (q2 < P && __float_as_uint(v2) >= thr)  partial += v2;
        if (q3 < P && __float_as_uint(v3) >= thr)  partial += v3;
    }
    #pragma unroll
    for (int o = 32; o; o >>= 1) partial += __shfl_down(partial, o);
    __shared__ float wsum[16];
    if ((t & 63) == 0) wsum[t >> 6] = partial;
    __syncthreads();
    if (t == 0) {
        float s = 0.f;
        #pragma unroll
        for (int i = 0; i < 16; ++i) s += wsum[i];
        if (s != 0.f) atomicAdd(&sums[2], (double)s);
    }
}

__global__ __launch_bounds__(64)
void k_final(const double* __restrict__ sums, const int* __restrict__ pos_total,
             float* __restrict__ out) {
    if (threadIdx.x == 0 && blockIdx.x == 0) {
        int np = *pos_total;
        if (np < 1) np = 1;
        out[0] = (float)((sums[0] + sums[1] + sums[2]) / (double)np);
    }
}

extern "C" void kernel_launch(void* const* d_in, const int* in_sizes, int n_in,
                              void* d_out, int out_size, void* d_ws, size_t ws_size,
                              hipStream_t stream) {
    const float* loc_preds     = (const float*)d_in[0];
    const float* conf_preds    = (const float*)d_in[1];
    const float* gt_boxes      = (const float*)d_in[2];
    const int*   gt_labels     = (const int*)d_in[3];
    const float* default_boxes = (const float*)d_in[4];

    int P = in_sizes[4] / 4;                // 24564
    int B = in_sizes[0] / (P * 4);          // 64
    int M = in_sizes[3] / B;                // 50
    int BM = B * M;

    // workspace carve-out (~12.6 MB)
    char* w = (char*)d_ws;
    double* sums      = (double*)w;            w += 3 * sizeof(double);
    int*    pos_total = (int*)w;               w += sizeof(int);
    int*    row_pos   = (int*)w;               w += (size_t)B * sizeof(int);
    w = (char*)(((uintptr_t)w + 7) & ~(uintptr_t)7);
    u64*  bp_key  = (u64*)w;                   w += (size_t)BM * 8;
    int*  bt_code = (int*)w;                   w += (size_t)B * P * 4;
    float* ce_neg = (float*)w;                 w += (size_t)B * P * 4;

    k_init<<<(BM + 255) / 256, 256, 0, stream>>>(bp_key, row_pos, pos_total, sums, B, M);

    dim3 g1((P + NPB - 1) / NPB, B);
    k_match<<<g1, NPB, 0, stream>>>((const float4*)default_boxes, (const float4*)gt_boxes,
                                    bt_code, bp_key, P, M);
    k_force2<<<(BM + 255) / 256, 256, 0, stream>>>(bp_key, bt_code, P, M, BM);
    k_loss<<<g1, NPB, 0, stream>>>(conf_preds, (const float4*)loc_preds,
                                   (const float4*)default_boxes, (const float4*)gt_boxes,
                                   gt_labels, bt_code, ce_neg, row_pos, pos_total,
                                   sums, P, M);
    k_select<<<B, 1024, 0, stream>>>(ce_neg, row_pos, sums, P);
    k_final<<<1, 64, 0, stream>>>(sums, pos_total, (float*)d_out);
}

// Round 3
// 536.475 us; speedup vs baseline: 1.3946x; 1.2778x over previous
//
#include <hip/hip_runtime.h>
#include <cstdint>

// MultiBoxLoss (SSD) for MI355X — round 3.
// B=64, P=24564, C=21, M=50. Output: scalar f32.
//
// Pipeline:
//   k_init    : zero accumulators
//   k_matchA  : per (b,p): best-truth over M via cross-mult compare -> bt_code (m or -1)
//   k_argmaxB : per (b, m-pair): argmax_p IoU via block reduction -> bp_idx  (no atomics)
//   k_force2  : per (b,m): atomicMax(&bt_code[b,p*], FORCED+m)  (max-m == last-m-wins)
//   k_loss    : wave-uniform global_load_lds staging (1KB/instr) -> logsumexp -> ce;
//               pos -> smooth-L1; ce_neg write; block-reduced atomics
//   k_select  : per-row radix-select k-th largest of ce_neg (k=3*row_pos), float4 loads
//   k_final   : (loc + ce_pos + ce_neg_sel) / max(num_pos,1)

static constexpr int NPB    = 256;         // priors per block
static constexpr int KC     = 21;          // classes
static constexpr int MAXM   = 64;          // >= M
static constexpr int FORCED = 0x40000000;  // forced-match code offset

typedef unsigned int       u32;
typedef unsigned long long u64;

#define GLOAD_LDS16(gp, lp)                                                        \
  __builtin_amdgcn_global_load_lds((const __attribute__((address_space(1))) u32*)(gp), \
                                   (__attribute__((address_space(3))) u32*)(lp), 16, 0, 0)

__global__ __launch_bounds__(256)
void k_init(int* row_pos, int* pos_total, double* sums, int B) {
    int i = threadIdx.x;
    if (i < B) row_pos[i] = 0;
    if (i == 0) { *pos_total = 0; sums[0] = 0.0; sums[1] = 0.0; sums[2] = 0.0; }
}

// Phase A: per-prior best truth (argmax over m, first-m ties), no divisions.
__global__ __launch_bounds__(256)
void k_matchA(const float4* __restrict__ dbox, const float4* __restrict__ gbox,
              int* __restrict__ bt_code, int P, int M) {
    int b = blockIdx.y;
    int t = threadIdx.x;
    int p = blockIdx.x * NPB + t;
    __shared__ float4 sg[MAXM];
    __shared__ float  sga[MAXM];
    if (t < M) {
        float4 g = gbox[b * M + t];
        sg[t]  = g;
        sga[t] = (g.z - g.x) * (g.w - g.y);
    }
    __syncthreads();
    if (p >= P) return;
    float4 d = dbox[p];
    float ad = (d.z - d.x) * (d.w - d.y);
    float bi = 0.f, bu = 1.f;   // best (inter, union); ratio compare via cross-mult
    int bm = 0;
    for (int m = 0; m < M; ++m) {
        float4 g = sg[m];
        float lx = fmaxf(d.x, g.x), ly = fmaxf(d.y, g.y);
        float rx = fminf(d.z, g.z), ry = fminf(d.w, g.w);
        float w = fmaxf(rx - lx, 0.f), h = fmaxf(ry - ly, 0.f);
        float inter = w * h;
        float uni = ad + sga[m] - inter;
        if (inter * bu > bi * uni) { bi = inter; bu = uni; bm = m; }  // strict >: first m wins
    }
    // pos iff iou >= 0.5  <=>  2*inter >= union
    bt_code[(size_t)b * P + p] = (2.f * bi >= bu) ? bm : -1;
}

// Phase B: per-(b,m) argmax over all P priors (first-p ties). MU=2 truths per block.
__global__ __launch_bounds__(256)
void k_argmaxB(const float4* __restrict__ dbox, const float4* __restrict__ gbox,
               int* __restrict__ bp_idx, int P, int M) {
    int b  = blockIdx.y;
    int m0 = blockIdx.x * 2;
    int t  = threadIdx.x;
    bool two = (m0 + 1) < M;
    float4 g0 = gbox[b * M + m0];
    float4 g1 = two ? gbox[b * M + m0 + 1] : g0;
    float ga0 = (g0.z - g0.x) * (g0.w - g0.y);
    float ga1 = (g1.z - g1.x) * (g1.w - g1.y);
    float bi0 = 0.f, bu0 = 1.f, bi1 = 0.f, bu1 = 1.f;
    int bp0 = 0x7FFFFFFF, bp1 = 0x7FFFFFFF;
    for (int p = t; p < P; p += NPB) {
        float4 d = dbox[p];
        float ad = (d.z - d.x) * (d.w - d.y);
        {
            float lx = fmaxf(d.x, g0.x), ly = fmaxf(d.y, g0.y);
            float rx = fminf(d.z, g0.z), ry = fminf(d.w, g0.w);
            float w = fmaxf(rx - lx, 0.f), h = fmaxf(ry - ly, 0.f);
            float inter = w * h;
            float uni = ad + ga0 - inter;
            float l = inter * bu0, r = bi0 * uni;
            if (l > r || (l == r && p < bp0)) { bi0 = inter; bu0 = uni; bp0 = p; }
        }
        {
            float lx = fmaxf(d.x, g1.x), ly = fmaxf(d.y, g1.y);
            float rx = fminf(d.z, g1.z), ry = fminf(d.w, g1.w);
            float w = fmaxf(rx - lx, 0.f), h = fmaxf(ry - ly, 0.f);
            float inter = w * h;
            float uni = ad + ga1 - inter;
            float l = inter * bu1, r = bi1 * uni;
            if (l > r || (l == r && p < bp1)) { bi1 = inter; bu1 = uni; bp1 = p; }
        }
    }
    #pragma unroll
    for (int o = 32; o; o >>= 1) {   // 64-lane butterfly, lexicographic (-iou, p)
        float oi0 = __shfl_xor(bi0, o), ou0 = __shfl_xor(bu0, o);
        int   op0 = __shfl_xor(bp0, o);
        float l0 = oi0 * bu0, r0 = bi0 * ou0;
        if (l0 > r0 || (l0 == r0 && op0 < bp0)) { bi0 = oi0; bu0 = ou0; bp0 = op0; }
        float oi1 = __shfl_xor(bi1, o), ou1 = __shfl_xor(bu1, o);
        int   op1 = __shfl_xor(bp1, o);
        float l1 = oi1 * bu1, r1 = bi1 * ou1;
        if (l1 > r1 || (l1 == r1 && op1 < bp1)) { bi1 = oi1; bu1 = ou1; bp1 = op1; }
    }
    __shared__ float wi[2][4], wu[2][4];
    __shared__ int   wp[2][4];
    int wid = t >> 6;
    if ((t & 63) == 0) {
        wi[0][wid] = bi0; wu[0][wid] = bu0; wp[0][wid] = bp0;
        wi[1][wid] = bi1; wu[1][wid] = bu1; wp[1][wid] = bp1;
    }
    __syncthreads();
    if (t == 0) {
        #pragma unroll
        for (int w = 1; w < 4; ++w) {
            float l = wi[0][w] * bu0, r = bi0 * wu[0][w];
            if (l > r || (l == r && wp[0][w] < bp0)) { bi0 = wi[0][w]; bu0 = wu[0][w]; bp0 = wp[0][w]; }
        }
        bp_idx[b * M + m0] = bp0;
        if (two) {
            #pragma unroll
            for (int w = 1; w < 4; ++w) {
                float l = wi[1][w] * bu1, r = bi1 * wu[1][w];
                if (l > r || (l == r && wp[1][w] < bp1)) { bi1 = wi[1][w]; bu1 = wu[1][w]; bp1 = wp[1][w]; }
            }
            bp_idx[b * M + m0 + 1] = bp1;
        }
    }
}

__global__ __launch_bounds__(256)
void k_force2(const int* __restrict__ bp_idx, int* __restrict__ bt_code, int P, int M, int BM) {
    int i = blockIdx.x * blockDim.x + threadIdx.x;
    if (i >= BM) return;
    int b = i / M, m = i - b * M;
    int p = bp_idx[i];
    atomicMax(&bt_code[(size_t)b * P + p], FORCED + m);  // max m == sequential last-m-wins
}

__global__ __launch_bounds__(256)
void k_loss(const float* __restrict__ conf, const float4* __restrict__ locp,
            const float4* __restrict__ dbox, const float4* __restrict__ gbox,
            const int* __restrict__ glab, const int* __restrict__ bt_code,
            float* __restrict__ ce_neg, int* __restrict__ row_pos,
            int* __restrict__ pos_total, double* __restrict__ sums, int P, int M) {
    int b  = blockIdx.y;
    int t  = threadIdx.x;
    int p0 = blockIdx.x * NPB;
    int npr = min(NPB, P - p0);
    __shared__ float slog[NPB * KC];  // 21504 B, linear (global_load_lds writes base+lane*16)
    const float* src = conf + ((size_t)b * P + p0) * KC;  // 16B-aligned (84*256 % 16 == 0)
    int nbytes = npr * KC * 4;
    int wave = t >> 6, lane = t & 63;
    int nfull = nbytes >> 10;                      // full 1KB chunks (one per wave-instr)
    for (int j = wave; j < nfull; j += 4) {
        int boff = __builtin_amdgcn_readfirstlane(j << 10);   // UNIFORM LDS offset
        const float* g = src + (boff >> 2) + lane * 4;        // per-lane global addr
        GLOAD_LDS16(g, (char*)slog + boff);
    }
    int rem16 = (nbytes & 1023) >> 4;              // leftover 16B units
    if (wave == 0 && lane < rem16) {
        int boff = __builtin_amdgcn_readfirstlane(nfull << 10);
        const float* g = src + (boff >> 2) + lane * 4;
        GLOAD_LDS16(g, (char*)slog + boff);
    }
    int donew = (nfull << 8) + (rem16 << 2);       // dwords staged
    for (int i = donew + t; i < (nbytes >> 2); i += NPB) slog[i] = src[i];  // safety tail
    __syncthreads();  // drains vmcnt/lgkmcnt -> LDS valid

    float sl1 = 0.f, cep = 0.f, posf = 0.f;
    if (t < npr) {
        int p = p0 + t;
        int code = bt_code[(size_t)b * P + p];
        bool pos = code >= 0;
        int  mi  = (code >= FORCED) ? (code - FORCED) : code;
        const float* L = slog + t * KC;  // stride 21 dwords: odd -> 2-way LDS alias (free)
        float v[KC];
        #pragma unroll
        for (int c = 0; c < KC; ++c) v[c] = L[c];   // static indexing only
        float mx = v[0];
        #pragma unroll
        for (int c = 1; c < KC; ++c) mx = fmaxf(mx, v[c]);
        float s = 0.f;
        #pragma unroll
        for (int c = 0; c < KC; ++c) s += __expf(v[c] - mx);
        int lab = pos ? glab[b * M + mi] : 0;
        float ce = mx + __logf(s) - L[lab];
        ce_neg[(size_t)b * P + p] = pos ? 0.f : ce;
        if (pos) {
            posf = 1.f;
            cep  = ce;
            float4 g = gbox[b * M + mi];
            float4 d = dbox[p];
            float gw = g.z - g.x, gh = g.w - g.y;
            float dw = d.z - d.x, dh = d.w - d.y;
            float e0 = (0.5f * (g.x + g.z) - 0.5f * (d.x + d.z)) / (0.1f * dw);
            float e1 = (0.5f * (g.y + g.w) - 0.5f * (d.y + d.w)) / (0.1f * dh);
            float e2 = __logf(gw / dw) * 5.0f;  // /VAR1=0.2
            float e3 = __logf(gh / dh) * 5.0f;
            float4 lp = locp[(size_t)b * P + p];
            float d0 = fabsf(lp.x - e0), d1 = fabsf(lp.y - e1);
            float d2 = fabsf(lp.z - e2), d3 = fabsf(lp.w - e3);
            sl1  = (d0 < 1.f ? 0.5f * d0 * d0 : d0 - 0.5f);
            sl1 += (d1 < 1.f ? 0.5f * d1 * d1 : d1 - 0.5f);
            sl1 += (d2 < 1.f ? 0.5f * d2 * d2 : d2 - 0.5f);
            sl1 += (d3 < 1.f ? 0.5f * d3 * d3 : d3 - 0.5f);
        }
    }
    #pragma unroll
    for (int o = 32; o; o >>= 1) {
        sl1  += __shfl_down(sl1, o);
        cep  += __shfl_down(cep, o);
        posf += __shfl_down(posf, o);
    }
    __shared__ float red[3][4];
    int wid = t >> 6;
    if ((t & 63) == 0) { red[0][wid] = sl1; red[1][wid] = cep; red[2][wid] = posf; }
    __syncthreads();
    if (t == 0) {
        float A  = red[0][0] + red[0][1] + red[0][2] + red[0][3];
        float Cc = red[1][0] + red[1][1] + red[1][2] + red[1][3];
        float Pp = red[2][0] + red[2][1] + red[2][2] + red[2][3];
        int pc = (int)(Pp + 0.5f);
        if (A  != 0.f) atomicAdd(&sums[0], (double)A);
        if (Cc != 0.f) atomicAdd(&sums[1], (double)Cc);
        if (pc) { atomicAdd(&row_pos[b], pc); atomicAdd(pos_total, pc); }
    }
}

__global__ __launch_bounds__(1024)
void k_select(const float* __restrict__ ce_neg, const int* __restrict__ row_pos,
              double* __restrict__ sums, int P) {
    const int NT = 1024, NW = 16;
    int b = blockIdx.x, t = threadIdx.x;
    int wid = t >> 6;
    __shared__ int hist[NW][256];
    __shared__ int sscan[256];
    __shared__ u32 s_prefix;
    __shared__ int s_krem;
    const float*  row  = ce_neg + (size_t)b * P;
    const float4* row4 = (const float4*)row;
    int P4 = P >> 2;                      // P % 4 == 0
    int k = 3 * row_pos[b];
    u32 thr;
    if (k <= 0) {
        thr = 0xFFFFFFFFu;   // select none
    } else if (k >= P) {
        thr = 0u;            // select all; positives contribute 0
    } else {
        if (t == 0) { s_prefix = 0u; s_krem = k; }
        for (int d = 3; d >= 0; --d) {  // MSB-first radix over float bits (all >= 0)
            for (int i = t; i < NW * 256; i += NT) ((int*)hist)[i] = 0;
            __syncthreads();
            u32 pre  = s_prefix;
            int krem = s_krem;
            u32 maskhi = (d == 3) ? 0u : (0xFFFFFFFFu << ((d + 1) * 8));
            int sh = 8 * d;
            int* h = hist[wid];
            for (int q = t; q < P4; q += NT) {        // float4: 4x fewer load instrs
                float4 v = row4[q];
                u32 w0 = __float_as_uint(v.x), w1 = __float_as_uint(v.y);
                u32 w2 = __float_as_uint(v.z), w3 = __float_as_uint(v.w);
                if ((w0 & maskhi) == pre) atomicAdd(&h[(w0 >> sh) & 255], 1);
                if ((w1 & maskhi) == pre) atomicAdd(&h[(w1 >> sh) & 255], 1);
                if ((w2 & maskhi) == pre) atomicAdd(&h[(w2 >> sh) & 255], 1);
                if ((w3 & maskhi) == pre) atomicAdd(&h[(w3 >> sh) & 255], 1);
            }
            __syncthreads();
            if (t < 256) {
                int c = 0;
                #pragma unroll
                for (int w = 0; w < NW; ++w) c += hist[w][t];
                sscan[t] = c;
            }
            __syncthreads();
            for (int off = 1; off < 256; off <<= 1) {  // parallel suffix scan
                int x = 0;
                if (t < 256) { x = sscan[t]; if (t + off < 256) x += sscan[t + off]; }
                __syncthreads();
                if (t < 256) sscan[t] = x;
                __syncthreads();
            }
            if (t < 256) {
                int S  = sscan[t];
                int Sn = (t < 255) ? sscan[t + 1] : 0;
                if (S >= krem && Sn < krem) {   // unique boundary bin
                    s_prefix = pre | ((u32)t << sh);
                    s_krem   = krem - Sn;
                }
            }
            __syncthreads();
        }
        thr = s_prefix;  // bits of k-th largest value
    }
    float partial = 0.f;
    for (int q = t; q < P4; q += NT) {
        float4 v = row4[q];
        if (__float_as_uint(v.x) >= thr) partial += v.x;
        if (__float_as_uint(v.y) >= thr) partial += v.y;
        if (__float_as_uint(v.z) >= thr) partial += v.z;
        if (__float_as_uint(v.w) >= thr) partial += v.w;
    }
    #pragma unroll
    for (int o = 32; o; o >>= 1) partial += __shfl_down(partial, o);
    __shared__ float wsum[16];
    if ((t & 63) == 0) wsum[t >> 6] = partial;
    __syncthreads();
    if (t == 0) {
        float s = 0.f;
        #pragma unroll
        for (int i = 0; i < 16; ++i) s += wsum[i];
        if (s != 0.f) atomicAdd(&sums[2], (double)s);
    }
}

__global__ __launch_bounds__(64)
void k_final(const double* __restrict__ sums, const int* __restrict__ pos_total,
             float* __restrict__ out) {
    if (threadIdx.x == 0 && blockIdx.x == 0) {
        int np = *pos_total;
        if (np < 1) np = 1;
        out[0] = (float)((sums[0] + sums[1] + sums[2]) / (double)np);
    }
}

extern "C" void kernel_launch(void* const* d_in, const int* in_sizes, int n_in,
                              void* d_out, int out_size, void* d_ws, size_t ws_size,
                              hipStream_t stream) {
    const float* loc_preds     = (const float*)d_in[0];
    const float* conf_preds    = (const float*)d_in[1];
    const float* gt_boxes      = (const float*)d_in[2];
    const int*   gt_labels     = (const int*)d_in[3];
    const float* default_boxes = (const float*)d_in[4];

    int P = in_sizes[4] / 4;                // 24564
    int B = in_sizes[0] / (P * 4);          // 64
    int M = in_sizes[3] / B;                // 50
    int BM = B * M;

    // workspace carve-out (~12.6 MB)
    char* w = (char*)d_ws;
    double* sums      = (double*)w;            w += 3 * sizeof(double);
    int*    pos_total = (int*)w;               w += sizeof(int);
    int*    row_pos   = (int*)w;               w += (size_t)B * sizeof(int);
    w = (char*)(((uintptr_t)w + 7) & ~(uintptr_t)7);
    int*  bp_idx  = (int*)w;                   w += (size_t)BM * sizeof(int);
    int*  bt_code = (int*)w;                   w += (size_t)B * P * 4;
    float* ce_neg = (float*)w;                 w += (size_t)B * P * 4;

    k_init<<<1, 256, 0, stream>>>(row_pos, pos_total, sums, B);

    dim3 g1((P + NPB - 1) / NPB, B);
    k_matchA<<<g1, NPB, 0, stream>>>((const float4*)default_boxes, (const float4*)gt_boxes,
                                     bt_code, P, M);
    dim3 g2((M + 1) / 2, B);
    k_argmaxB<<<g2, NPB, 0, stream>>>((const float4*)default_boxes, (const float4*)gt_boxes,
                                      bp_idx, P, M);
    k_force2<<<(BM + 255) / 256, 256, 0, stream>>>(bp_idx, bt_code, P, M, BM);
    k_loss<<<g1, NPB, 0, stream>>>(conf_preds, (const float4*)loc_preds,
                                   (const float4*)default_boxes, (const float4*)gt_boxes,
                                   gt_labels, bt_code, ce_neg, row_pos, pos_total,
                                   sums, P, M);
    k_select<<<B, 1024, 0, stream>>>(ce_neg, row_pos, sums, P);
    k_final<<<1, 64, 0, stream>>>(sums, pos_total, (float*)d_out);
}

// Round 4
// 345.898 us; speedup vs baseline: 2.1630x; 1.5510x over previous
//
#include <hip/hip_runtime.h>
#include <cstdint>

// MultiBoxLoss (SSD) for MI355X — round 4.
// B=64, P=24564, C=21, M=50. Output: scalar f32.
//
// Pipeline (NO contended global atomics anywhere):
//   k_matchA  : per (b,p): best-truth over M via cross-mult compare -> bt_code (m or -1)
//   k_argmaxB : per (b, m-pair): argmax_p IoU via block reduction -> bp_idx
//   k_force2  : per (b,m): atomicMax(&bt_code[b,p*], FORCED+m) (sparse, uncontended)
//   k_loss    : staged conf -> logsumexp -> ce; pos -> smooth-L1; ce_neg write;
//               per-block partials WRITTEN (not atomic'd): partials[blk], poscnt[blk]
//   k_select  : per-row: row_pos = sum(poscnt row); radix-select k-th largest of
//               ce_neg (k=3*row_pos); negsum[b] = sum of selected
//   k_final   : f64 reduce partials + negsum + row_pos -> scalar
//
// All ws cells written unconditionally every launch (ws is re-poisoned 0xAA).

static constexpr int NPB    = 256;         // priors per block
static constexpr int KC     = 21;          // classes
static constexpr int MAXM   = 64;          // >= M
static constexpr int FORCED = 0x40000000;  // forced-match code offset

typedef unsigned int       u32;
typedef unsigned long long u64;

#define GLOAD_LDS16(gp, lp)                                                        \
  __builtin_amdgcn_global_load_lds((const __attribute__((address_space(1))) u32*)(gp), \
                                   (__attribute__((address_space(3))) u32*)(lp), 16, 0, 0)

// Phase A: per-prior best truth (argmax over m, first-m ties), no divisions.
__global__ __launch_bounds__(256)
void k_matchA(const float4* __restrict__ dbox, const float4* __restrict__ gbox,
              int* __restrict__ bt_code, int P, int M) {
    int b = blockIdx.y;
    int t = threadIdx.x;
    int p = blockIdx.x * NPB + t;
    __shared__ float4 sg[MAXM];
    __shared__ float  sga[MAXM];
    if (t < M) {
        float4 g = gbox[b * M + t];
        sg[t]  = g;
        sga[t] = (g.z - g.x) * (g.w - g.y);
    }
    __syncthreads();
    if (p >= P) return;
    float4 d = dbox[p];
    float ad = (d.z - d.x) * (d.w - d.y);
    float bi = 0.f, bu = 1.f;   // best (inter, union); ratio compare via cross-mult
    int bm = 0;
    for (int m = 0; m < M; ++m) {
        float4 g = sg[m];
        float lx = fmaxf(d.x, g.x), ly = fmaxf(d.y, g.y);
        float rx = fminf(d.z, g.z), ry = fminf(d.w, g.w);
        float w = fmaxf(rx - lx, 0.f), h = fmaxf(ry - ly, 0.f);
        float inter = w * h;
        float uni = ad + sga[m] - inter;
        if (inter * bu > bi * uni) { bi = inter; bu = uni; bm = m; }  // strict >: first m wins
    }
    // pos iff iou >= 0.5  <=>  2*inter >= union
    bt_code[(size_t)b * P + p] = (2.f * bi >= bu) ? bm : -1;
}

// Phase B: per-(b,m) argmax over all P priors (first-p ties). 2 truths per block.
__global__ __launch_bounds__(256)
void k_argmaxB(const float4* __restrict__ dbox, const float4* __restrict__ gbox,
               int* __restrict__ bp_idx, int P, int M) {
    int b  = blockIdx.y;
    int m0 = blockIdx.x * 2;
    int t  = threadIdx.x;
    bool two = (m0 + 1) < M;
    float4 g0 = gbox[b * M + m0];
    float4 g1 = two ? gbox[b * M + m0 + 1] : g0;
    float ga0 = (g0.z - g0.x) * (g0.w - g0.y);
    float ga1 = (g1.z - g1.x) * (g1.w - g1.y);
    float bi0 = 0.f, bu0 = 1.f, bi1 = 0.f, bu1 = 1.f;
    int bp0 = 0x7FFFFFFF, bp1 = 0x7FFFFFFF;
    for (int p = t; p < P; p += NPB) {
        float4 d = dbox[p];
        float ad = (d.z - d.x) * (d.w - d.y);
        {
            float lx = fmaxf(d.x, g0.x), ly = fmaxf(d.y, g0.y);
            float rx = fminf(d.z, g0.z), ry = fminf(d.w, g0.w);
            float w = fmaxf(rx - lx, 0.f), h = fmaxf(ry - ly, 0.f);
            float inter = w * h;
            float uni = ad + ga0 - inter;
            float l = inter * bu0, r = bi0 * uni;
            if (l > r || (l == r && p < bp0)) { bi0 = inter; bu0 = uni; bp0 = p; }
        }
        {
            float lx = fmaxf(d.x, g1.x), ly = fmaxf(d.y, g1.y);
            float rx = fminf(d.z, g1.z), ry = fminf(d.w, g1.w);
            float w = fmaxf(rx - lx, 0.f), h = fmaxf(ry - ly, 0.f);
            float inter = w * h;
            float uni = ad + ga1 - inter;
            float l = inter * bu1, r = bi1 * uni;
            if (l > r || (l == r && p < bp1)) { bi1 = inter; bu1 = uni; bp1 = p; }
        }
    }
    #pragma unroll
    for (int o = 32; o; o >>= 1) {   // 64-lane butterfly, lexicographic (-iou, p)
        float oi0 = __shfl_xor(bi0, o), ou0 = __shfl_xor(bu0, o);
        int   op0 = __shfl_xor(bp0, o);
        float l0 = oi0 * bu0, r0 = bi0 * ou0;
        if (l0 > r0 || (l0 == r0 && op0 < bp0)) { bi0 = oi0; bu0 = ou0; bp0 = op0; }
        float oi1 = __shfl_xor(bi1, o), ou1 = __shfl_xor(bu1, o);
        int   op1 = __shfl_xor(bp1, o);
        float l1 = oi1 * bu1, r1 = bi1 * ou1;
        if (l1 > r1 || (l1 == r1 && op1 < bp1)) { bi1 = oi1; bu1 = ou1; bp1 = op1; }
    }
    __shared__ float wi[2][4], wu[2][4];
    __shared__ int   wp[2][4];
    int wid = t >> 6;
    if ((t & 63) == 0) {
        wi[0][wid] = bi0; wu[0][wid] = bu0; wp[0][wid] = bp0;
        wi[1][wid] = bi1; wu[1][wid] = bu1; wp[1][wid] = bp1;
    }
    __syncthreads();
    if (t == 0) {
        #pragma unroll
        for (int w = 1; w < 4; ++w) {
            float l = wi[0][w] * bu0, r = bi0 * wu[0][w];
            if (l > r || (l == r && wp[0][w] < bp0)) { bi0 = wi[0][w]; bu0 = wu[0][w]; bp0 = wp[0][w]; }
        }
        bp_idx[b * M + m0] = bp0;
        if (two) {
            #pragma unroll
            for (int w = 1; w < 4; ++w) {
                float l = wi[1][w] * bu1, r = bi1 * wu[1][w];
                if (l > r || (l == r && wp[1][w] < bp1)) { bi1 = wi[1][w]; bu1 = wu[1][w]; bp1 = wp[1][w]; }
            }
            bp_idx[b * M + m0 + 1] = bp1;
        }
    }
}

__global__ __launch_bounds__(256)
void k_force2(const int* __restrict__ bp_idx, int* __restrict__ bt_code, int P, int M, int BM) {
    int i = blockIdx.x * blockDim.x + threadIdx.x;
    if (i >= BM) return;
    int b = i / M, m = i - b * M;
    int p = bp_idx[i];
    atomicMax(&bt_code[(size_t)b * P + p], FORCED + m);  // max m == sequential last-m-wins
}

__global__ __launch_bounds__(256)
void k_loss(const float* __restrict__ conf, const float4* __restrict__ locp,
            const float4* __restrict__ dbox, const float4* __restrict__ gbox,
            const int* __restrict__ glab, const int* __restrict__ bt_code,
            float* __restrict__ ce_neg, float2* __restrict__ partials,
            int* __restrict__ poscnt, int P, int M) {
    int b  = blockIdx.y;
    int t  = threadIdx.x;
    int p0 = blockIdx.x * NPB;
    int npr = min(NPB, P - p0);
    __shared__ float slog[NPB * KC];  // 21504 B, linear (global_load_lds: base+lane*16)
    const float* src = conf + ((size_t)b * P + p0) * KC;  // 16B-aligned (84*256 % 16 == 0)
    int nbytes = npr * KC * 4;
    int wave = t >> 6, lane = t & 63;
    int nfull = nbytes >> 10;                      // full 1KB chunks (one per wave-instr)
    for (int j = wave; j < nfull; j += 4) {
        int boff = __builtin_amdgcn_readfirstlane(j << 10);   // UNIFORM LDS offset
        const float* g = src + (boff >> 2) + lane * 4;        // per-lane global addr
        GLOAD_LDS16(g, (char*)slog + boff);
    }
    int rem16 = (nbytes & 1023) >> 4;              // leftover 16B units
    if (wave == 0 && lane < rem16) {
        int boff = __builtin_amdgcn_readfirstlane(nfull << 10);
        const float* g = src + (boff >> 2) + lane * 4;
        GLOAD_LDS16(g, (char*)slog + boff);
    }
    int donew = (nfull << 8) + (rem16 << 2);       // dwords staged
    for (int i = donew + t; i < (nbytes >> 2); i += NPB) slog[i] = src[i];  // safety tail
    __syncthreads();  // drains vmcnt/lgkmcnt -> LDS valid

    float sl1 = 0.f, cep = 0.f, posf = 0.f;
    if (t < npr) {
        int p = p0 + t;
        int code = bt_code[(size_t)b * P + p];
        bool pos = code >= 0;
        int  mi  = (code >= FORCED) ? (code - FORCED) : code;
        const float* L = slog + t * KC;  // stride 21 dwords: odd -> 2-way LDS alias (free)
        float v[KC];
        #pragma unroll
        for (int c = 0; c < KC; ++c) v[c] = L[c];
        float mx = v[0];
        #pragma unroll
        for (int c = 1; c < KC; ++c) mx = fmaxf(mx, v[c]);
        float s = 0.f;
        #pragma unroll
        for (int c = 0; c < KC; ++c) s += __expf(v[c] - mx);
        int lab = pos ? glab[b * M + mi] : 0;
        float ce = mx + __logf(s) - L[lab];
        ce_neg[(size_t)b * P + p] = pos ? 0.f : ce;
        if (pos) {
            posf = 1.f;
            cep  = ce;
            float4 g = gbox[b * M + mi];
            float4 d = dbox[p];
            float gw = g.z - g.x, gh = g.w - g.y;
            float dw = d.z - d.x, dh = d.w - d.y;
            float e0 = (0.5f * (g.x + g.z) - 0.5f * (d.x + d.z)) / (0.1f * dw);
            float e1 = (0.5f * (g.y + g.w) - 0.5f * (d.y + d.w)) / (0.1f * dh);
            float e2 = __logf(gw / dw) * 5.0f;  // /VAR1=0.2
            float e3 = __logf(gh / dh) * 5.0f;
            float4 lp = locp[(size_t)b * P + p];
            float d0 = fabsf(lp.x - e0), d1 = fabsf(lp.y - e1);
            float d2 = fabsf(lp.z - e2), d3 = fabsf(lp.w - e3);
            sl1  = (d0 < 1.f ? 0.5f * d0 * d0 : d0 - 0.5f);
            sl1 += (d1 < 1.f ? 0.5f * d1 * d1 : d1 - 0.5f);
            sl1 += (d2 < 1.f ? 0.5f * d2 * d2 : d2 - 0.5f);
            sl1 += (d3 < 1.f ? 0.5f * d3 * d3 : d3 - 0.5f);
        }
    }
    #pragma unroll
    for (int o = 32; o; o >>= 1) {
        sl1  += __shfl_down(sl1, o);
        cep  += __shfl_down(cep, o);
        posf += __shfl_down(posf, o);
    }
    __shared__ float red[3][4];
    int wid = t >> 6;
    if ((t & 63) == 0) { red[0][wid] = sl1; red[1][wid] = cep; red[2][wid] = posf; }
    __syncthreads();
    if (t == 0) {
        float A  = red[0][0] + red[0][1] + red[0][2] + red[0][3];
        float Cc = red[1][0] + red[1][1] + red[1][2] + red[1][3];
        float Pp = red[2][0] + red[2][1] + red[2][2] + red[2][3];
        int blk = blockIdx.y * gridDim.x + blockIdx.x;
        partials[blk] = make_float2(A, Cc);     // plain stores — NO atomics
        poscnt[blk]   = (int)(Pp + 0.5f);
    }
}

__global__ __launch_bounds__(1024)
void k_select(const float* __restrict__ ce_neg, const int* __restrict__ poscnt,
              int* __restrict__ row_pos, float* __restrict__ negsum, int P, int NBX) {
    const int NT = 1024, NW = 16;
    int b = blockIdx.x, t = threadIdx.x;
    int wid = t >> 6;
    __shared__ int hist[NW][256];
    __shared__ int sscan[256];
    __shared__ u32 s_prefix;
    __shared__ int s_krem;
    __shared__ int s_k;
    __shared__ float wsum[16];

    // row_pos[b] = sum of this row's per-block pos counts (NBX ints)
    {
        int c = 0;
        for (int i = t; i < NBX; i += NT) c += poscnt[b * NBX + i];
        #pragma unroll
        for (int o = 32; o; o >>= 1) c += __shfl_down(c, o);
        if ((t & 63) == 0) ((int*)wsum)[wid] = c;
        __syncthreads();
        if (t == 0) {
            int s = 0;
            #pragma unroll
            for (int i = 0; i < NW; ++i) s += ((int*)wsum)[i];
            s_k = s;
            row_pos[b] = s;
        }
        __syncthreads();
    }
    int k = 3 * s_k;

    const float*  row  = ce_neg + (size_t)b * P;
    const float4* row4 = (const float4*)row;
    int P4 = P >> 2;                      // P % 4 == 0
    u32 thr;
    if (k <= 0) {
        thr = 0xFFFFFFFFu;   // select none (finite non-neg bits < 0xFFFFFFFF)
    } else if (k >= P) {
        thr = 0u;            // select all; positives contribute 0
    } else {
        if (t == 0) { s_prefix = 0u; s_krem = k; }
        for (int d = 3; d >= 0; --d) {  // MSB-first radix over float bits (all >= 0)
            for (int i = t; i < NW * 256; i += NT) ((int*)hist)[i] = 0;
            __syncthreads();
            u32 pre  = s_prefix;
            int krem = s_krem;
            u32 maskhi = (d == 3) ? 0u : (0xFFFFFFFFu << ((d + 1) * 8));
            int sh = 8 * d;
            int* h = hist[wid];
            for (int q = t; q < P4; q += NT) {
                float4 v = row4[q];
                u32 w0 = __float_as_uint(v.x), w1 = __float_as_uint(v.y);
                u32 w2 = __float_as_uint(v.z), w3 = __float_as_uint(v.w);
                if ((w0 & maskhi) == pre) atomicAdd(&h[(w0 >> sh) & 255], 1);
                if ((w1 & maskhi) == pre) atomicAdd(&h[(w1 >> sh) & 255], 1);
                if ((w2 & maskhi) == pre) atomicAdd(&h[(w2 >> sh) & 255], 1);
                if ((w3 & maskhi) == pre) atomicAdd(&h[(w3 >> sh) & 255], 1);
            }
            __syncthreads();
            if (t < 256) {
                int c = 0;
                #pragma unroll
                for (int w = 0; w < NW; ++w) c += hist[w][t];
                sscan[t] = c;
            }
            __syncthreads();
            for (int off = 1; off < 256; off <<= 1) {  // parallel suffix scan
                int x = 0;
                if (t < 256) { x = sscan[t]; if (t + off < 256) x += sscan[t + off]; }
                __syncthreads();
                if (t < 256) sscan[t] = x;
                __syncthreads();
            }
            if (t < 256) {
                int S  = sscan[t];
                int Sn = (t < 255) ? sscan[t + 1] : 0;
                if (S >= krem && Sn < krem) {   // unique boundary bin
                    s_prefix = pre | ((u32)t << sh);
                    s_krem   = krem - Sn;
                }
            }
            __syncthreads();
        }
        thr = s_prefix;  // bits of k-th largest value
    }
    float partial = 0.f;
    for (int q = t; q < P4; q += NT) {
        float4 v = row4[q];
        if (__float_as_uint(v.x) >= thr) partial += v.x;
        if (__float_as_uint(v.y) >= thr) partial += v.y;
        if (__float_as_uint(v.z) >= thr) partial += v.z;
        if (__float_as_uint(v.w) >= thr) partial += v.w;
    }
    #pragma unroll
    for (int o = 32; o; o >>= 1) partial += __shfl_down(partial, o);
    __syncthreads();
    if ((t & 63) == 0) wsum[wid] = partial;
    __syncthreads();
    if (t == 0) {
        float s = 0.f;
        #pragma unroll
        for (int i = 0; i < 16; ++i) s += wsum[i];
        negsum[b] = s;                  // plain store — NO atomic
    }
}

__global__ __launch_bounds__(256)
void k_final(const float2* __restrict__ partials, const int* __restrict__ row_pos,
             const float* __restrict__ negsum, int nblk, int B, float* __restrict__ out) {
    int t = threadIdx.x;
    double a = 0.0, c = 0.0;
    for (int i = t; i < nblk; i += 256) {
        float2 p = partials[i];
        a += (double)p.x;
        c += (double)p.y;
    }
    double ns = 0.0;
    int np = 0;
    for (int i = t; i < B; i += 256) { ns += (double)negsum[i]; np += row_pos[i]; }
    #pragma unroll
    for (int o = 32; o; o >>= 1) {
        a  += __shfl_down(a, o);
        c  += __shfl_down(c, o);
        ns += __shfl_down(ns, o);
        np += __shfl_down(np, o);
    }
    __shared__ double red[3][4];
    __shared__ int    redn[4];
    int wid = t >> 6;
    if ((t & 63) == 0) { red[0][wid] = a; red[1][wid] = c; red[2][wid] = ns; redn[wid] = np; }
    __syncthreads();
    if (t == 0) {
        double A = red[0][0] + red[0][1] + red[0][2] + red[0][3];
        double C = red[1][0] + red[1][1] + red[1][2] + red[1][3];
        double N = red[2][0] + red[2][1] + red[2][2] + red[2][3];
        int    P_ = redn[0] + redn[1] + redn[2] + redn[3];
        if (P_ < 1) P_ = 1;
        out[0] = (float)((A + C + N) / (double)P_);
    }
}

extern "C" void kernel_launch(void* const* d_in, const int* in_sizes, int n_in,
                              void* d_out, int out_size, void* d_ws, size_t ws_size,
                              hipStream_t stream) {
    const float* loc_preds     = (const float*)d_in[0];
    const float* conf_preds    = (const float*)d_in[1];
    const float* gt_boxes      = (const float*)d_in[2];
    const int*   gt_labels     = (const int*)d_in[3];
    const float* default_boxes = (const float*)d_in[4];

    int P = in_sizes[4] / 4;                // 24564
    int B = in_sizes[0] / (P * 4);          // 64
    int M = in_sizes[3] / B;                // 50
    int BM  = B * M;
    int NBX = (P + NPB - 1) / NPB;          // 96
    int nblk = NBX * B;                     // 6144

    // workspace carve-out (~12.8 MB)
    char* w = (char*)d_ws;
    float2* partials = (float2*)w;             w += (size_t)nblk * sizeof(float2);
    int*    poscnt   = (int*)w;                w += (size_t)nblk * sizeof(int);
    int*    row_pos  = (int*)w;                w += (size_t)B * sizeof(int);
    float*  negsum   = (float*)w;              w += (size_t)B * sizeof(float);
    int*    bp_idx   = (int*)w;                w += (size_t)BM * sizeof(int);
    int*    bt_code  = (int*)w;                w += (size_t)B * P * 4;
    float*  ce_neg   = (float*)w;              w += (size_t)B * P * 4;

    dim3 g1(NBX, B);
    k_matchA<<<g1, NPB, 0, stream>>>((const float4*)default_boxes, (const float4*)gt_boxes,
                                     bt_code, P, M);
    dim3 g2((M + 1) / 2, B);
    k_argmaxB<<<g2, NPB, 0, stream>>>((const float4*)default_boxes, (const float4*)gt_boxes,
                                      bp_idx, P, M);
    k_force2<<<(BM + 255) / 256, 256, 0, stream>>>(bp_idx, bt_code, P, M, BM);
    k_loss<<<g1, NPB, 0, stream>>>(conf_preds, (const float4*)loc_preds,
                                   (const float4*)default_boxes, (const float4*)gt_boxes,
                                   gt_labels, bt_code, ce_neg, partials, poscnt, P, M);
    k_select<<<B, 1024, 0, stream>>>(ce_neg, poscnt, row_pos, negsum, P, NBX);
    k_final<<<1, 256, 0, stream>>>(partials, row_pos, negsum, nblk, B, (float*)d_out);
}